// Round 2
// baseline (888.271 us; speedup 1.0000x reference)
//
#include <hip/hip_runtime.h>
#include <cstdint>
#include <cstddef>

#define Tn 1024
#define Hn 2048
#define En 8
#define In 1408
#define ISn 5632

typedef __attribute__((ext_vector_type(8))) short bf16x8;
typedef __attribute__((ext_vector_type(4))) float f32x4;

__device__ __forceinline__ unsigned short f2bf(float f) {
  unsigned u = __builtin_bit_cast(unsigned, f);
  u += 0x7fffu + ((u >> 16) & 1u);
  return (unsigned short)(u >> 16);
}

#define PK2(a, b) ((unsigned)f2bf(a) | ((unsigned)f2bf(b) << 16))
// XOR swizzle within 128B rows: 16B chunk index ^= (row & 7)
#define SWZ(row, bir) (((row) << 7) | ((((bir) >> 4) ^ ((row) & 7)) << 4) | ((bir) & 15))

// ---------------- router: fp32 logits, softmax, top-2, shared sigmoid gate ----
__global__ void router_kernel(const float* __restrict__ x, const float* __restrict__ gw,
                              const float* __restrict__ sgw, float* __restrict__ logits_out,
                              float* __restrict__ combine, float* __restrict__ sgate) {
  int t = blockIdx.x;
  int l = threadIdx.x;
  const float* xr = x + (size_t)t * Hn;
  float acc[En];
#pragma unroll
  for (int e = 0; e < En; ++e) acc[e] = 0.f;
  float accs = 0.f;
  for (int h = l; h < Hn; h += 64) {
    float xv = xr[h];
    const float4 g0 = *(const float4*)(gw + (size_t)h * En);
    const float4 g1 = *(const float4*)(gw + (size_t)h * En + 4);
    acc[0] += xv * g0.x; acc[1] += xv * g0.y; acc[2] += xv * g0.z; acc[3] += xv * g0.w;
    acc[4] += xv * g1.x; acc[5] += xv * g1.y; acc[6] += xv * g1.z; acc[7] += xv * g1.w;
    accs += xv * sgw[h];
  }
#pragma unroll
  for (int e = 0; e < En; ++e) {
#pragma unroll
    for (int off = 32; off > 0; off >>= 1) acc[e] += __shfl_down(acc[e], off);
  }
#pragma unroll
  for (int off = 32; off > 0; off >>= 1) accs += __shfl_down(accs, off);
  if (l == 0) {
    float mx = acc[0];
#pragma unroll
    for (int e = 1; e < En; ++e) mx = fmaxf(mx, acc[e]);
    float p[En], s = 0.f;
#pragma unroll
    for (int e = 0; e < En; ++e) { p[e] = expf(acc[e] - mx); s += p[e]; }
    float inv = 1.f / s;
#pragma unroll
    for (int e = 0; e < En; ++e) p[e] *= inv;
    int i1 = 0;
#pragma unroll
    for (int e = 1; e < En; ++e) if (p[e] > p[i1]) i1 = e;     // strict > : lowest idx wins ties
    int i2 = (i1 == 0) ? 1 : 0;
#pragma unroll
    for (int e = 0; e < En; ++e) if (e != i1 && p[e] > p[i2]) i2 = e;
#pragma unroll
    for (int e = 0; e < En; ++e)
      combine[t * En + e] = (e == i1 || e == i2) ? p[e] : 0.f;
    sgate[t] = 1.f / (1.f + expf(-accs));
#pragma unroll
    for (int e = 0; e < En; ++e) logits_out[t * En + e] = acc[e];
  }
}

// ---------------- x -> bf16 ----------------
__global__ void cvt_x_kernel(const float* __restrict__ x, unsigned short* __restrict__ xb) {
  int i = (blockIdx.x * 256 + threadIdx.x) << 2;
  float4 v = *(const float4*)(x + i);
  ushort4 o;
  o.x = f2bf(v.x); o.y = f2bf(v.y); o.z = f2bf(v.z); o.w = f2bf(v.w);
  *(ushort4*)(xb + i) = o;
}

// Stage a 64k x 128n fp32 tile -> LDS as B^T [128n][64k] bf16, XOR-swizzled.
// Each of 256 threads: 8k x 4n block. Global: half-wave reads 512B contiguous.
// LDS writes are ds_write_b128, ~4-way (at LDS BW limit).
__device__ __forceinline__ void stage_b(char* sB, const float* __restrict__ src, int ldb, int tid) {
  const int kb = tid >> 5;      // 0..7  (k-chunk of 8)
  const int nb = tid & 31;      // 0..31 (n-chunk of 4)
  const float* p = src + (size_t)(kb * 8) * ldb + nb * 4;
  float4 r0 = *(const float4*)p; p += ldb;
  float4 r1 = *(const float4*)p; p += ldb;
  float4 r2 = *(const float4*)p; p += ldb;
  float4 r3 = *(const float4*)p; p += ldb;
  float4 r4 = *(const float4*)p; p += ldb;
  float4 r5 = *(const float4*)p; p += ldb;
  float4 r6 = *(const float4*)p; p += ldb;
  float4 r7 = *(const float4*)p;
  uint4 pk;
  int n, off;
#define STORE_ROW(J, F)                                                        \
  n = nb * 4 + (J);                                                            \
  pk.x = PK2(r0.F, r1.F); pk.y = PK2(r2.F, r3.F);                              \
  pk.z = PK2(r4.F, r5.F); pk.w = PK2(r6.F, r7.F);                              \
  off = (n << 7) | (((kb ^ (n & 7)) << 4));                                    \
  *(uint4*)(sB + off) = pk;
  STORE_ROW(0, x)
  STORE_ROW(1, y)
  STORE_ROW(2, z)
  STORE_ROW(3, w)
#undef STORE_ROW
}

// ---------------- fused gate/up GEMM: act = bf16(scale * silu(x@Wg) * (x@Wu)) --
// mode 0: per-expert (blockIdx.y = e), scale = combine[t*8+e], N = In
// mode 1: shared expert, scale = sgate[t], N = ISn
__global__ __launch_bounds__(256, 2)
void gateup_kernel(const unsigned short* __restrict__ xb,
                   const float* __restrict__ Wg, const float* __restrict__ Wu,
                   const float* __restrict__ combine, const float* __restrict__ sgate,
                   unsigned short* __restrict__ actout, int N, int mode) {
  __shared__ char smem[48 * 1024];
  char* sA = smem;
  char* sBg = smem + 16 * 1024;
  char* sBu = smem + 32 * 1024;

  const int tid = threadIdx.x;
  const int lane = tid & 63;
  const int wid = tid >> 6;
  const int wm = wid >> 1, wn = wid & 1;
  const int e = blockIdx.y;
  const int ntiles = N >> 7;
  const int mt = blockIdx.x / ntiles;
  const int nt = blockIdx.x - mt * ntiles;
  const int m0 = mt << 7, n0 = nt << 7;

  const float* Bg0 = Wg + (size_t)e * Hn * N + n0;
  const float* Bu0 = Wu + (size_t)e * Hn * N + n0;
  unsigned short* aout = actout + (size_t)e * Tn * N;

  f32x4 accg[4][4], accu[4][4];
#pragma unroll
  for (int i = 0; i < 4; ++i)
#pragma unroll
    for (int j = 0; j < 4; ++j) {
      accg[i][j] = {0.f, 0.f, 0.f, 0.f};
      accu[i][j] = {0.f, 0.f, 0.f, 0.f};
    }

  for (int kt = 0; kt < Hn / 64; ++kt) {
    const int k0 = kt << 6;
    // stage A (bf16 copy, swizzled)
#pragma unroll
    for (int q = 0; q < 4; ++q) {
      int cc = tid + (q << 8);
      int row = cc >> 3, c = cc & 7;
      uint4 v = *(const uint4*)(xb + (size_t)(m0 + row) * Hn + k0 + (c << 3));
      *(uint4*)(sA + SWZ(row, c << 4)) = v;
    }
    stage_b(sBg, Bg0 + (size_t)k0 * N, N, tid);
    stage_b(sBu, Bu0 + (size_t)k0 * N, N, tid);
    __syncthreads();
#pragma unroll
    for (int kk = 0; kk < 2; ++kk) {
      bf16x8 af[4], bg[4], bu[4];
      const int bir = (kk << 6) + ((lane >> 4) << 4);
#pragma unroll
      for (int mi = 0; mi < 4; ++mi) {
        int row = (wm << 6) + (mi << 4) + (lane & 15);
        af[mi] = *(const bf16x8*)(sA + SWZ(row, bir));
      }
#pragma unroll
      for (int ni = 0; ni < 4; ++ni) {
        int n = (wn << 6) + (ni << 4) + (lane & 15);
        bg[ni] = *(const bf16x8*)(sBg + SWZ(n, bir));
        bu[ni] = *(const bf16x8*)(sBu + SWZ(n, bir));
      }
#pragma unroll
      for (int mi = 0; mi < 4; ++mi)
#pragma unroll
        for (int ni = 0; ni < 4; ++ni) {
          accg[mi][ni] = __builtin_amdgcn_mfma_f32_16x16x32_bf16(af[mi], bg[ni], accg[mi][ni], 0, 0, 0);
          accu[mi][ni] = __builtin_amdgcn_mfma_f32_16x16x32_bf16(af[mi], bu[ni], accu[mi][ni], 0, 0, 0);
        }
    }
    __syncthreads();
  }

  // epilogue: scale * silu(g) * u -> bf16
#pragma unroll
  for (int mi = 0; mi < 4; ++mi)
#pragma unroll
    for (int ni = 0; ni < 4; ++ni)
#pragma unroll
      for (int r = 0; r < 4; ++r) {
        int m = m0 + (wm << 6) + (mi << 4) + ((lane >> 4) << 2) + r;
        int n = n0 + (wn << 6) + (ni << 4) + (lane & 15);
        float sc = (mode == 0) ? combine[(m << 3) + e] : sgate[m];
        float g = accg[mi][ni][r];
        float u = accu[mi][ni][r];
        float val = sc * (g / (1.f + __expf(-g))) * u;
        aout[(size_t)m * N + n] = f2bf(val);
      }
}

// ---------------- concatenated down GEMM: out = actE@wd (8 slabs) + actS@sd ---
// K = 8*1408 + 5632 = 16896; split-K=2 (boundary at 6*1408) + atomicAdd
__global__ __launch_bounds__(256, 2)
void down_kernel(const unsigned short* __restrict__ act, const unsigned short* __restrict__ acts,
                 const float* __restrict__ wd, const float* __restrict__ sd,
                 float* __restrict__ out) {
  __shared__ char smem[32 * 1024];
  char* sA = smem;
  char* sB = smem + 16 * 1024;

  const int tid = threadIdx.x;
  const int lane = tid & 63;
  const int wid = tid >> 6;
  const int wm = wid >> 1, wn = wid & 1;
  const int mt = blockIdx.x >> 4, nt = blockIdx.x & 15;
  const int m0 = mt << 7, n0 = nt << 7;
  const int ktBeg = blockIdx.y * 132, ktEnd = ktBeg + 132;

  f32x4 acc[4][4];
#pragma unroll
  for (int i = 0; i < 4; ++i)
#pragma unroll
    for (int j = 0; j < 4; ++j) acc[i][j] = {0.f, 0.f, 0.f, 0.f};

  for (int kt = ktBeg; kt < ktEnd; ++kt) {
    const int k0 = kt << 6;
    const unsigned short* aSrc;
    const float* bSrc;
    int lda;
    if (k0 < En * In) {
      int ex = k0 / In;
      int i0 = k0 - ex * In;
      aSrc = act + ((size_t)ex * Tn + m0) * In + i0;
      lda = In;
      bSrc = wd + ((size_t)ex * In + i0) * Hn + n0;
    } else {
      int j0 = k0 - En * In;
      aSrc = acts + (size_t)m0 * ISn + j0;
      lda = ISn;
      bSrc = sd + (size_t)j0 * Hn + n0;
    }
#pragma unroll
    for (int q = 0; q < 4; ++q) {
      int cc = tid + (q << 8);
      int row = cc >> 3, c = cc & 7;
      uint4 v = *(const uint4*)(aSrc + (size_t)row * lda + (c << 3));
      *(uint4*)(sA + SWZ(row, c << 4)) = v;
    }
    stage_b(sB, bSrc, Hn, tid);
    __syncthreads();
#pragma unroll
    for (int kk = 0; kk < 2; ++kk) {
      bf16x8 af[4], bf[4];
      const int bir = (kk << 6) + ((lane >> 4) << 4);
#pragma unroll
      for (int mi = 0; mi < 4; ++mi) {
        int row = (wm << 6) + (mi << 4) + (lane & 15);
        af[mi] = *(const bf16x8*)(sA + SWZ(row, bir));
      }
#pragma unroll
      for (int ni = 0; ni < 4; ++ni) {
        int n = (wn << 6) + (ni << 4) + (lane & 15);
        bf[ni] = *(const bf16x8*)(sB + SWZ(n, bir));
      }
#pragma unroll
      for (int mi = 0; mi < 4; ++mi)
#pragma unroll
        for (int ni = 0; ni < 4; ++ni)
          acc[mi][ni] = __builtin_amdgcn_mfma_f32_16x16x32_bf16(af[mi], bf[ni], acc[mi][ni], 0, 0, 0);
    }
    __syncthreads();
  }

#pragma unroll
  for (int mi = 0; mi < 4; ++mi)
#pragma unroll
    for (int ni = 0; ni < 4; ++ni)
#pragma unroll
      for (int r = 0; r < 4; ++r) {
        int m = m0 + (wm << 6) + (mi << 4) + ((lane >> 4) << 2) + r;
        int n = n0 + (wn << 6) + (ni << 4) + (lane & 15);
        atomicAdd(out + (size_t)m * Hn + n, acc[mi][ni][r]);
      }
}

extern "C" void kernel_launch(void* const* d_in, const int* in_sizes, int n_in,
                              void* d_out, int out_size, void* d_ws, size_t ws_size,
                              hipStream_t stream) {
  const float* x   = (const float*)d_in[0];
  const float* gw  = (const float*)d_in[1];
  const float* wg  = (const float*)d_in[2];
  const float* wu  = (const float*)d_in[3];
  const float* wd  = (const float*)d_in[4];
  const float* sg  = (const float*)d_in[5];
  const float* su  = (const float*)d_in[6];
  const float* sd  = (const float*)d_in[7];
  const float* sgw = (const float*)d_in[8];
  float* out = (float*)d_out;
  float* logits_out = out + (size_t)Tn * Hn;   // final [2,512,2048] then logits [1024,8]

  char* w = (char*)d_ws;
  float* combine = (float*)w;                              // T*E fp32
  float* sgate = combine + Tn * En;                        // T fp32
  unsigned short* xb   = (unsigned short*)(w + 64 * 1024); // T*H bf16 (4 MB)
  unsigned short* actE = xb + (size_t)Tn * Hn;             // E*T*I bf16 (23.1 MB)
  unsigned short* actS = actE + (size_t)En * Tn * In;      // T*IS bf16 (11.5 MB)

  hipMemsetAsync(d_out, 0, (size_t)out_size * sizeof(float), stream);
  router_kernel<<<Tn, 64, 0, stream>>>(x, gw, sgw, logits_out, combine, sgate);
  cvt_x_kernel<<<(Tn * Hn / 4) / 256, 256, 0, stream>>>(x, xb);
  // experts: grid.x = (T/128)*(I/128) = 8*11, grid.y = 8
  gateup_kernel<<<dim3(8 * (In / 128), En), 256, 0, stream>>>(xb, wg, wu, combine, sgate, actE, In, 0);
  // shared: grid.x = 8*(IS/128) = 8*44
  gateup_kernel<<<dim3(8 * (ISn / 128), 1), 256, 0, stream>>>(xb, sg, su, combine, sgate, actS, ISn, 1);
  // down: 8*16 tiles, split-K = 2
  down_kernel<<<dim3(128, 2), 256, 0, stream>>>(actE, actS, wd, sd, out);
}